// Round 11
// baseline (75.641 us; speedup 1.0000x reference)
//
#include <hip/hip_runtime.h>
#include <hip/hip_bf16.h>

#define T_SEQ 2048
#define EMB   128
#define H     16
#define BATCH 8
#define VSTR  2064        // Vt row stride (elems), non-power-of-2 (r11)
// Q pre-scale: 1/sqrt(16) * log2(e)  -> scores in log2 domain
#define QSCALE 0.360673760222241f

// exp2 via clang builtin (r8-proven); __exp2f clashes with glibc macro.
#define EXP2F(x) __builtin_amdgcn_exp2f(x)

typedef short short8_t __attribute__((ext_vector_type(8)));  // 8 bf16
typedef float f32x4    __attribute__((ext_vector_type(4)));  // MFMA C/D frag

__device__ __forceinline__ unsigned short f2bf(float f) {
    __hip_bfloat16 h = __float2bfloat16(f);   // RNE
    return *reinterpret_cast<unsigned short*>(&h);
}

// ---------------------------------------------------------------------------
// Kernel 1 (r23): QKV projection, 4 row-groups per block.
// 256 blocks x 768t (12 waves): wave w -> group g=w/3, matrix m=w%3.
// Body is the r15-proven MFMA projection (no LDS, no barriers).
// Dispatch-count ladder: r15 1024 -> r22 512 -> r23 256 blocks.
// ---------------------------------------------------------------------------
__global__ __launch_bounds__(768) void qkv_kernel(
    const float* __restrict__ x,
    const float* __restrict__ Wq,
    const float* __restrict__ Wk,
    const float* __restrict__ Wv,
    unsigned short* __restrict__ Qbf,
    unsigned short* __restrict__ Kbf,
    unsigned short* __restrict__ Vt)
{
    const int tid  = threadIdx.x;
    const int w    = tid >> 6;        // 0..11
    const int grp  = w / 3;           // 0..3 (row-group within block)
    const int m    = w - 3 * grp;     // 0:Q 1:K 2:V
    const int lane = tid & 63;
    const int q    = lane >> 4;
    const int n    = lane & 15;
    const int r0   = (blockIdx.x * 4 + grp) * 16;

    const float* Wm = (m == 0) ? Wq : (m == 1) ? Wk : Wv;
    const float* xr = x + (size_t)(r0 + n) * EMB;

    f32x4 a = {0.f, 0.f, 0.f, 0.f};
#pragma unroll
    for (int t = 0; t < 4; ++t) {
        const int k0 = t * 32 + q * 8;
        float4 xa = *reinterpret_cast<const float4*>(xr + k0);
        float4 xb = *reinterpret_cast<const float4*>(xr + k0 + 4);
        union { unsigned short s[8]; short8_t v; } xf;
        xf.s[0]=f2bf(xa.x); xf.s[1]=f2bf(xa.y); xf.s[2]=f2bf(xa.z); xf.s[3]=f2bf(xa.w);
        xf.s[4]=f2bf(xb.x); xf.s[5]=f2bf(xb.y); xf.s[6]=f2bf(xb.z); xf.s[7]=f2bf(xb.w);
        // B fragment: lane(q,n) needs W[k0+j][n], j=0..7 (row stride H=16).
        union { unsigned short s[8]; short8_t v; } wf;
#pragma unroll
        for (int j = 0; j < 8; ++j)
            wf.s[j] = f2bf(Wm[(size_t)(k0 + j) * H + n]);
        a = __builtin_amdgcn_mfma_f32_16x16x32_bf16(xf.v, wf.v, a, 0, 0, 0);
    }

    // C/D frag: lane(q,n) holds rows r0+4q+r, col n.
    const int grow = r0 + q * 4;
    if (m == 0) {
#pragma unroll
        for (int r = 0; r < 4; ++r)
            Qbf[(size_t)(grow + r) * H + n] = f2bf(a[r] * QSCALE);
    } else if (m == 1) {
#pragma unroll
        for (int r = 0; r < 4; ++r)
            Kbf[(size_t)(grow + r) * H + n] = f2bf(a[r]);
    } else {
        const int b   = grow >> 11;
        const int ib0 = grow & 2047;
        union { unsigned short s[4]; unsigned long long u; } vp;
        vp.s[0]=f2bf(a[0]); vp.s[1]=f2bf(a[1]); vp.s[2]=f2bf(a[2]); vp.s[3]=f2bf(a[3]);
        *reinterpret_cast<unsigned long long*>(
            Vt + ((size_t)b * H + n) * VSTR + ib0) = vp.u;
    }
}

// ---------------------------------------------------------------------------
// Kernel 2 (r23): split-K flash attention, FOUR tiles per block (2 phases).
// 256 blocks x 512t (8 waves): waves 0-3 = group 0, waves 4-7 = group 1.
//   phase 0: group0 -> tile bid       (nc 1..4),  group1 -> 511-bid  (nc 5..8)
//   phase 1: group0 -> tile 512+bid   (nc 9..12), group1 -> 1023-bid (nc 13..16)
// Within a phase the groups differ by <=4 chunks = <=1 wave-iteration after
// the 4-way split, so the phase barrier costs ~1 iter. Each group-tile runs
// the r16-proven body verbatim (K prefetch, no-max log2 softmax, plain-sum
// combine). LDS: r19-proven P/comb union, re-used across phases with a
// trailing barrier protecting the next phase's P writes.
// Dispatch-count ladder: r16 1024 -> r22 512 -> r23 256 blocks.
// ---------------------------------------------------------------------------
__global__ __launch_bounds__(512, 4) void attn_fused(
    const unsigned short* __restrict__ Qbf,
    const unsigned short* __restrict__ Kbf,
    const unsigned short* __restrict__ Vt,
    float* __restrict__ out)
{
    __shared__ union {
        unsigned int P[8][16][68];             // 34.8 KB wave-private P^T
        struct {
            float A[8][16][20];                // padded: bank-spread
            float L[8][16];
        } comb;
    } sh;

    const int tid  = threadIdx.x;
    const int wv   = tid >> 6;                 // 0..7
    const int tl   = wv >> 2;                  // group 0/1
    const int sp   = wv & 3;                   // split index 0..3
    const int lane = tid & 63;
    const int q    = lane >> 4;
    const int n    = lane & 15;
    const int bid  = blockIdx.x;               // 0..255

    for (int ph = 0; ph < 2; ++ph) {
        // Tile assignment (see header): balanced within each phase.
        const int gt = (ph == 0) ? (tl ? (511 - bid) : bid)
                                 : (tl ? (1023 - bid) : (512 + bid));
        const int b    = gt & 7;               // batch
        const int qt   = gt >> 3;              // Q tile 0..127
        const int i0   = qt << 4;
        const int nc   = (qt >> 3) + 1;        // chunks of 128 K cols
        const int irow = i0 + n;

        const unsigned short* Qp = Qbf + (size_t)b * T_SEQ * H;
        const unsigned short* Kp = Kbf + (size_t)b * T_SEQ * H;
        const unsigned short* vrow = Vt + (size_t)b * H * VSTR + (size_t)n * VSTR;

        // Q loaded once per tile (4 waves share 16 rows; L1-resident).
        short8_t qf = {0,0,0,0,0,0,0,0};
        if (q < 2)
            qf = *reinterpret_cast<const short8_t*>(Qp + (size_t)irow * H + q * 8);

        f32x4 acc = {0.f, 0.f, 0.f, 0.f};      // O^T fragment (fp32, carried)
        float l = 0.f;                         // per-lane partial denom

        // K prefetch prologue: first chunk's 8 fragments into registers.
        int c = sp;
        short8_t kcur[8];
#pragma unroll
        for (int s = 0; s < 8; ++s) kcur[s] = (short8_t){0,0,0,0,0,0,0,0};
        if (c < nc && q < 2) {
            const int j0 = c << 7;
#pragma unroll
            for (int s = 0; s < 8; ++s)
                kcur[s] = *reinterpret_cast<const short8_t*>(
                              Kp + (size_t)(j0 + s * 16 + n) * H + q * 8);
        }

        for (; c < nc; c += 4) {
            const int j0 = c << 7;

            // S MFMAs consume the prefetched K fragments.
            f32x4 S[8];
#pragma unroll
            for (int s = 0; s < 8; ++s) {
                f32x4 z = {0.f, 0.f, 0.f, 0.f};
                S[s] = __builtin_amdgcn_mfma_f32_16x16x32_bf16(kcur[s], qf, z, 0, 0, 0);
            }
            // Prefetch next chunk's K (hides under softmax+PV below).
            const int c2 = c + 4;
            if (c2 < nc && q < 2) {
                const int j2 = c2 << 7;
#pragma unroll
                for (int s = 0; s < 8; ++s)
                    kcur[s] = *reinterpret_cast<const short8_t*>(
                                  Kp + (size_t)(j2 + s * 16 + n) * H + q * 8);
            }
            // V fragments issued early (consumed after softmax).
            short8_t vf[4];
#pragma unroll
            for (int h = 0; h < 4; ++h)
                vf[h] = *reinterpret_cast<const short8_t*>(vrow + j0 + h * 32 + q * 8);

            // Causal mask: exactly the diagonal chunk satisfies j0+127 > i0.
            // Masked entries -> -1e30 -> exp2 flushes to exactly 0.
            if (j0 + 127 > i0) {
#pragma unroll
                for (int s = 0; s < 8; ++s) {
                    const int kb = j0 + s * 16 + q * 4;
#pragma unroll
                    for (int rr = 0; rr < 4; ++rr)
                        S[s][rr] = (kb + rr <= irow) ? S[s][rr] : -1e30f;
                }
            }

            // exp2 (no max shift needed in log2 domain), per-lane partial
            // sum, pack P^T into LDS (wave-private slice of sh.P).
            float lc = 0.f;
#pragma unroll
            for (int s = 0; s < 8; ++s) {
                float e0 = EXP2F(S[s][0]);
                float e1 = EXP2F(S[s][1]);
                float e2 = EXP2F(S[s][2]);
                float e3 = EXP2F(S[s][3]);
                lc += (e0 + e1) + (e2 + e3);
                unsigned int b0 = __builtin_bit_cast(unsigned int, e0);
                unsigned int b1 = __builtin_bit_cast(unsigned int, e1);
                unsigned int b2 = __builtin_bit_cast(unsigned int, e2);
                unsigned int b3 = __builtin_bit_cast(unsigned int, e3);
                unsigned long long pw =
                    (unsigned long long)((b1 & 0xffff0000u) | (b0 >> 16)) |
                    ((unsigned long long)((b3 & 0xffff0000u) | (b2 >> 16)) << 32);
                *reinterpret_cast<unsigned long long*>(&sh.P[wv][n][8 * s + 2 * q]) = pw;
            }
            l += lc;

            // PV: O^T += V^T · P^T (4 MFMAs, b128 P reads, C carries acc).
#pragma unroll
            for (int h = 0; h < 4; ++h) {
                uint4 p4 = *reinterpret_cast<const uint4*>(&sh.P[wv][n][16 * h + 4 * q]);
                union { uint4 u; short8_t v; } pu; pu.u = p4;
                acc = __builtin_amdgcn_mfma_f32_16x16x32_bf16(vf[h], pu.v, acc, 0, 0, 0);
            }
        }

        // Per-wave row denominator: sum partials across the 4 q lanes.
        l += __shfl_xor(l, 16);
        l += __shfl_xor(l, 32);

        // All waves done with sh.P before comb (aliased) is written.
        __syncthreads();

        // Publish wave partial: lane (q,n) holds O_w[row=i0+n][dim=4q+r].
        *reinterpret_cast<float4*>(&sh.comb.A[wv][n][4 * q]) =
            (float4){acc[0], acc[1], acc[2], acc[3]};
        if (q == 0) sh.comb.L[wv][n] = l;
        __syncthreads();

        // Combine per group: plain sums over its 4 wave partials.
        // 512 threads = 2 groups x 256 outputs (row, dim).
        {
            const int tile = tid >> 8;         // which group's tile
            const int row  = (tid >> 4) & 15;
            const int d    = tid & 15;
            const int gt2  = (ph == 0) ? (tile ? (511 - bid) : bid)
                                       : (tile ? (1023 - bid) : (512 + bid));
            const int b2   = gt2 & 7;
            const int i02  = (gt2 >> 3) << 4;
            float L = 0.f, O = 0.f;
#pragma unroll
            for (int w2 = 0; w2 < 4; ++w2) {
                L += sh.comb.L[4 * tile + w2][row];
                O += sh.comb.A[4 * tile + w2][row][d];
            }
            out[((size_t)b2 * T_SEQ + i02 + row) * H + d] = O / L;
        }

        // Protect next phase's P writes from this phase's comb reads.
        if (ph == 0) __syncthreads();
    }
}

// ---------------------------------------------------------------------------
extern "C" void kernel_launch(void* const* d_in, const int* in_sizes, int n_in,
                              void* d_out, int out_size, void* d_ws, size_t ws_size,
                              hipStream_t stream)
{
    const float* x  = (const float*)d_in[0];
    const float* Wq = (const float*)d_in[1];
    const float* Wk = (const float*)d_in[2];
    const float* Wv = (const float*)d_in[3];
    float* out = (float*)d_out;

    const size_t NE = (size_t)BATCH * T_SEQ * H;      // 262144 elems per buf
    unsigned short* Qbf = (unsigned short*)d_ws;
    unsigned short* Kbf = Qbf + NE;
    unsigned short* Vt  = Kbf + NE;                   // BATCH*H*VSTR elems

    qkv_kernel<<<BATCH * T_SEQ / 64, 768, 0, stream>>>(
        x, Wq, Wk, Wv, Qbf, Kbf, Vt);
    attn_fused<<<T_SEQ / 16 * BATCH / 4, 512, 0, stream>>>(Qbf, Kbf, Vt, out);
}

// Round 12
// 72.760 us; speedup vs baseline: 1.0396x; 1.0396x over previous
//
#include <hip/hip_runtime.h>
#include <hip/hip_bf16.h>

#define T_SEQ 2048
#define EMB   128
#define H     16
#define BATCH 8
#define VSTR  2064        // Vt row stride (elems), non-power-of-2 (r11)
// Q pre-scale: 1/sqrt(16) * log2(e)  -> scores in log2 domain
#define QSCALE 0.360673760222241f

// exp2 via clang builtin (r8-proven); __exp2f clashes with glibc macro.
#define EXP2F(x) __builtin_amdgcn_exp2f(x)

typedef short short8_t __attribute__((ext_vector_type(8)));  // 8 bf16
typedef float f32x4    __attribute__((ext_vector_type(4)));  // MFMA C/D frag

__device__ __forceinline__ unsigned short f2bf(float f) {
    __hip_bfloat16 h = __float2bfloat16(f);   // RNE
    return *reinterpret_cast<unsigned short*>(&h);
}

// ---------------------------------------------------------------------------
// Kernel 1 (r24 = r22-proven): QKV projection, 2 row-groups per block.
// 512 blocks x 384t (6 waves): wave w -> group g=w/3, matrix m=w%3.
// Body is the r15-proven MFMA projection (no LDS, no barriers).
// ---------------------------------------------------------------------------
__global__ __launch_bounds__(384) void qkv_kernel(
    const float* __restrict__ x,
    const float* __restrict__ Wq,
    const float* __restrict__ Wk,
    const float* __restrict__ Wv,
    unsigned short* __restrict__ Qbf,
    unsigned short* __restrict__ Kbf,
    unsigned short* __restrict__ Vt)
{
    const int tid  = threadIdx.x;
    const int w    = tid >> 6;        // 0..5
    const int grp  = (w >= 3) ? 1 : 0;
    const int m    = w - 3 * grp;     // 0:Q 1:K 2:V
    const int lane = tid & 63;
    const int q    = lane >> 4;
    const int n    = lane & 15;
    const int r0   = (blockIdx.x * 2 + grp) * 16;

    const float* Wm = (m == 0) ? Wq : (m == 1) ? Wk : Wv;
    const float* xr = x + (size_t)(r0 + n) * EMB;

    f32x4 a = {0.f, 0.f, 0.f, 0.f};
#pragma unroll
    for (int t = 0; t < 4; ++t) {
        const int k0 = t * 32 + q * 8;
        float4 xa = *reinterpret_cast<const float4*>(xr + k0);
        float4 xb = *reinterpret_cast<const float4*>(xr + k0 + 4);
        union { unsigned short s[8]; short8_t v; } xf;
        xf.s[0]=f2bf(xa.x); xf.s[1]=f2bf(xa.y); xf.s[2]=f2bf(xa.z); xf.s[3]=f2bf(xa.w);
        xf.s[4]=f2bf(xb.x); xf.s[5]=f2bf(xb.y); xf.s[6]=f2bf(xb.z); xf.s[7]=f2bf(xb.w);
        // B fragment: lane(q,n) needs W[k0+j][n], j=0..7 (row stride H=16).
        union { unsigned short s[8]; short8_t v; } wf;
#pragma unroll
        for (int j = 0; j < 8; ++j)
            wf.s[j] = f2bf(Wm[(size_t)(k0 + j) * H + n]);
        a = __builtin_amdgcn_mfma_f32_16x16x32_bf16(xf.v, wf.v, a, 0, 0, 0);
    }

    // C/D frag: lane(q,n) holds rows r0+4q+r, col n.
    const int grow = r0 + q * 4;
    if (m == 0) {
#pragma unroll
        for (int r = 0; r < 4; ++r)
            Qbf[(size_t)(grow + r) * H + n] = f2bf(a[r] * QSCALE);
    } else if (m == 1) {
#pragma unroll
        for (int r = 0; r < 4; ++r)
            Kbf[(size_t)(grow + r) * H + n] = f2bf(a[r]);
    } else {
        const int b   = grow >> 11;
        const int ib0 = grow & 2047;
        union { unsigned short s[4]; unsigned long long u; } vp;
        vp.s[0]=f2bf(a[0]); vp.s[1]=f2bf(a[1]); vp.s[2]=f2bf(a[2]); vp.s[3]=f2bf(a[3]);
        *reinterpret_cast<unsigned long long*>(
            Vt + ((size_t)b * H + n) * VSTR + ib0) = vp.u;
    }
}

// ---------------------------------------------------------------------------
// Kernel 2 (r24): r22-proven two-tiles-per-block split-K flash attention
// + two VALU-chain reductions (R4-calibrated at ~2-3ns/critical-VALU-op):
//  (a) P pack via v_cvt_pk_bf16_f32 (1 inst for 2 f32->bf16x2; replaces
//      ~6 bit-ops per pair-group; RNE instead of truncation).
//  (b) denominator l computed on the MFMA pipe: one extra PV-style MFMA
//      per h with A = splat(1.0bf16): acc_l[r] = sum_k P[row n][k] —
//      replaces 32 scalar adds/chunk AND the 2 end shuffles (all lanes
//      get the full row sum; masked P entries are exactly 0).
// Structure unchanged from r22: 512 blocks x 512t, waves 0-3 -> tile bid,
// waves 4-7 -> tile 1023-bid (perfect balance, ncA+ncB=17), 4-way
// split-K per tile, K prefetch, no-max log2 softmax, plain-sum combine,
// P/comb LDS union.
// ---------------------------------------------------------------------------
__global__ __launch_bounds__(512, 4) void attn_fused(
    const unsigned short* __restrict__ Qbf,
    const unsigned short* __restrict__ Kbf,
    const unsigned short* __restrict__ Vt,
    float* __restrict__ out)
{
    __shared__ union {
        unsigned int P[8][16][68];             // 34.8 KB wave-private P^T
        struct {
            float A[8][16][20];                // padded: bank-spread
            float L[8][16];
        } comb;
    } sh;

    const int tid  = threadIdx.x;
    const int wv   = tid >> 6;                 // 0..7
    const int tl   = wv >> 2;                  // local tile 0/1
    const int sp   = wv & 3;                   // split index 0..3
    const int lane = tid & 63;
    const int q    = lane >> 4;
    const int n    = lane & 15;
    const int bid  = blockIdx.x;               // 0..511
    const int gt   = tl ? (1023 - bid) : bid;  // global tile 0..1023
    const int b    = gt & 7;                   // batch
    const int qt   = gt >> 3;                  // Q tile 0..127
    const int i0   = qt << 4;
    const int nc   = (qt >> 3) + 1;            // chunks of 128 K cols
    const int irow = i0 + n;

    const unsigned short* Qp = Qbf + (size_t)b * T_SEQ * H;
    const unsigned short* Kp = Kbf + (size_t)b * T_SEQ * H;
    const unsigned short* vrow = Vt + (size_t)b * H * VSTR + (size_t)n * VSTR;

    // Q loaded once (the tile's 4 waves read the same 16 rows; L1-resident).
    short8_t qf = {0,0,0,0,0,0,0,0};
    if (q < 2)
        qf = *reinterpret_cast<const short8_t*>(Qp + (size_t)irow * H + q * 8);

    // A-operand of the denominator MFMA: bf16 1.0 in every slot.
    const short8_t vones = {(short)0x3F80, (short)0x3F80, (short)0x3F80,
                            (short)0x3F80, (short)0x3F80, (short)0x3F80,
                            (short)0x3F80, (short)0x3F80};

    f32x4 acc  = {0.f, 0.f, 0.f, 0.f};         // O^T fragment (fp32, carried)
    f32x4 accl = {0.f, 0.f, 0.f, 0.f};         // row-sum fragment (denom)

    // K prefetch prologue: first chunk's 8 fragments into registers.
    int c = sp;
    short8_t kcur[8];
#pragma unroll
    for (int s = 0; s < 8; ++s) kcur[s] = (short8_t){0,0,0,0,0,0,0,0};
    if (c < nc && q < 2) {
        const int j0 = c << 7;
#pragma unroll
        for (int s = 0; s < 8; ++s)
            kcur[s] = *reinterpret_cast<const short8_t*>(
                          Kp + (size_t)(j0 + s * 16 + n) * H + q * 8);
    }

    for (; c < nc; c += 4) {
        const int j0 = c << 7;

        // S MFMAs consume the prefetched K fragments.
        f32x4 S[8];
#pragma unroll
        for (int s = 0; s < 8; ++s) {
            f32x4 z = {0.f, 0.f, 0.f, 0.f};
            S[s] = __builtin_amdgcn_mfma_f32_16x16x32_bf16(kcur[s], qf, z, 0, 0, 0);
        }
        // Prefetch next chunk's K (latency hides under softmax+PV below).
        const int c2 = c + 4;
        if (c2 < nc && q < 2) {
            const int j2 = c2 << 7;
#pragma unroll
            for (int s = 0; s < 8; ++s)
                kcur[s] = *reinterpret_cast<const short8_t*>(
                              Kp + (size_t)(j2 + s * 16 + n) * H + q * 8);
        }
        // V fragments issued early (consumed after softmax).
        short8_t vf[4];
#pragma unroll
        for (int h = 0; h < 4; ++h)
            vf[h] = *reinterpret_cast<const short8_t*>(vrow + j0 + h * 32 + q * 8);

        // Causal mask: exactly the diagonal chunk satisfies j0+127 > i0.
        // Masked entries -> -1e30 -> exp2 flushes to exactly 0.
        if (j0 + 127 > i0) {
#pragma unroll
            for (int s = 0; s < 8; ++s) {
                const int kb = j0 + s * 16 + q * 4;
#pragma unroll
                for (int rr = 0; rr < 4; ++rr)
                    S[s][rr] = (kb + rr <= irow) ? S[s][rr] : -1e30f;
            }
        }

        // exp2 (no max shift needed in log2 domain); pack P^T into LDS via
        // v_cvt_pk_bf16_f32 (RNE, 1 inst per f32 pair). No scalar l adds.
#pragma unroll
        for (int s = 0; s < 8; ++s) {
            float e0 = EXP2F(S[s][0]);
            float e1 = EXP2F(S[s][1]);
            float e2 = EXP2F(S[s][2]);
            float e3 = EXP2F(S[s][3]);
            unsigned int p01, p23;
            asm("v_cvt_pk_bf16_f32 %0, %1, %2" : "=v"(p01) : "v"(e0), "v"(e1));
            asm("v_cvt_pk_bf16_f32 %0, %1, %2" : "=v"(p23) : "v"(e2), "v"(e3));
            unsigned long long pw =
                (unsigned long long)p01 | ((unsigned long long)p23 << 32);
            *reinterpret_cast<unsigned long long*>(&sh.P[wv][n][8 * s + 2 * q]) = pw;
        }

        // PV: O^T += V^T · P^T, and denom row-sums on the same MFMA pipe.
#pragma unroll
        for (int h = 0; h < 4; ++h) {
            uint4 p4 = *reinterpret_cast<const uint4*>(&sh.P[wv][n][16 * h + 4 * q]);
            union { uint4 u; short8_t v; } pu; pu.u = p4;
            acc  = __builtin_amdgcn_mfma_f32_16x16x32_bf16(vf[h], pu.v, acc, 0, 0, 0);
            accl = __builtin_amdgcn_mfma_f32_16x16x32_bf16(vones, pu.v, accl, 0, 0, 0);
        }
    }

    // accl[r] = sum_k P[row n][k] for every (q,r) — full row denominator,
    // already reduced across all k slots (no shuffles needed).
    const float l = accl[0];

    // All waves must be done with sh.P before comb (aliased) is written.
    __syncthreads();

    // Publish wave partial: lane (q,n) holds O_w[row=i0+n][dim=4q+r].
    *reinterpret_cast<float4*>(&sh.comb.A[wv][n][4 * q]) =
        (float4){acc[0], acc[1], acc[2], acc[3]};
    if (q == 0) sh.comb.L[wv][n] = l;
    __syncthreads();

    // Combine per tile: plain sums over its 4 wave partials.
    // Thread tid -> (tile, row, dim); 512 threads = 2 tiles x 256 outputs.
    {
        const int tile = tid >> 8;
        const int row  = (tid >> 4) & 15;
        const int d    = tid & 15;
        const int gt2  = tile ? (1023 - bid) : bid;
        const int b2   = gt2 & 7;
        const int i02  = (gt2 >> 3) << 4;
        float L = 0.f, O = 0.f;
#pragma unroll
        for (int w2 = 0; w2 < 4; ++w2) {
            L += sh.comb.L[4 * tile + w2][row];
            O += sh.comb.A[4 * tile + w2][row][d];
        }
        out[((size_t)b2 * T_SEQ + i02 + row) * H + d] = O / L;
    }
}

// ---------------------------------------------------------------------------
extern "C" void kernel_launch(void* const* d_in, const int* in_sizes, int n_in,
                              void* d_out, int out_size, void* d_ws, size_t ws_size,
                              hipStream_t stream)
{
    const float* x  = (const float*)d_in[0];
    const float* Wq = (const float*)d_in[1];
    const float* Wk = (const float*)d_in[2];
    const float* Wv = (const float*)d_in[3];
    float* out = (float*)d_out;

    const size_t NE = (size_t)BATCH * T_SEQ * H;      // 262144 elems per buf
    unsigned short* Qbf = (unsigned short*)d_ws;
    unsigned short* Kbf = Qbf + NE;
    unsigned short* Vt  = Kbf + NE;                   // BATCH*H*VSTR elems

    qkv_kernel<<<BATCH * T_SEQ / 32, 384, 0, stream>>>(
        x, Wq, Wk, Wv, Qbf, Kbf, Vt);
    attn_fused<<<T_SEQ / 16 * BATCH / 2, 512, 0, stream>>>(Qbf, Kbf, Vt, out);
}